// Round 7
// baseline (334.139 us; speedup 1.0000x reference)
//
#include <hip/hip_runtime.h>
#include <hip/hip_bf16.h>

#define L_DIM 32
#define N_DIM 1024
#define D_DIM 768
#define K_DIM 16
#define I_DIM 64
#define O_DIM 64
#define EPSF 1e-8f
#define PX 72   // padded LDS row (bf16 elems): 144 B

typedef unsigned short u16;
typedef __attribute__((ext_vector_type(8))) short short8;   // 8 bf16 (4 VGPRs)
typedef __attribute__((ext_vector_type(4))) float f32x4;
#define MFMA __builtin_amdgcn_mfma_f32_16x16x32_bf16

__device__ __forceinline__ float bf2f(u16 v) {
    union { unsigned int u; float f; } x; x.u = ((unsigned int)v) << 16; return x.f;
}
__device__ __forceinline__ u16 f2bf(float f) {
    union { float f; unsigned int u; } x; x.f = f;
    unsigned int u = x.u;
    u += 0x7FFFu + ((u >> 16) & 1u);   // RNE
    return (u16)(u >> 16);
}
__device__ __forceinline__ void split2(float v, u16& h, u16& l) {
    u16 hh = f2bf(v);
    h = hh;
    l = f2bf(v - bf2f(hh));
}
// cheap truncation split of float4 -> packed hi uint2 + lo uint2 (exact residual)
__device__ __forceinline__ void store_split4(u16* ph, u16* pl, float4 v) {
    unsigned u0 = __float_as_uint(v.x), u1 = __float_as_uint(v.y);
    unsigned u2 = __float_as_uint(v.z), u3 = __float_as_uint(v.w);
    uint2 H, L;
    H.x = (u0 >> 16) | (u1 & 0xFFFF0000u);
    H.y = (u2 >> 16) | (u3 & 0xFFFF0000u);
    float l0 = v.x - __uint_as_float(u0 & 0xFFFF0000u);
    float l1 = v.y - __uint_as_float(u1 & 0xFFFF0000u);
    float l2 = v.z - __uint_as_float(u2 & 0xFFFF0000u);
    float l3 = v.w - __uint_as_float(u3 & 0xFFFF0000u);
    L.x = (__float_as_uint(l0) >> 16) | (__float_as_uint(l1) & 0xFFFF0000u);
    L.y = (__float_as_uint(l2) >> 16) | (__float_as_uint(l3) & 0xFFFF0000u);
    *(uint2*)ph = H;
    *(uint2*)pl = L;
}

// ---------------------------------------------------------------------------
// Prep (merged): blockIdx.x < 12 -> Wcap [l][d][i] -> [l][i][d] hi/lo
//                blockIdx.x >= 12 -> Wvote [l][k][i][o] -> [l][k][o][i] hi/lo
// grid (28, 32), 256 thr. Branch is block-uniform.
// ---------------------------------------------------------------------------
__global__ __launch_bounds__(256) void prep_w(
    const float* __restrict__ Wc, u16* __restrict__ cH, u16* __restrict__ cL,
    const float* __restrict__ Wv, u16* __restrict__ vH, u16* __restrict__ vL)
{
    const int l = blockIdx.y, t = threadIdx.x;
    __shared__ float tile[64][65];
    if (blockIdx.x < 12) {
        const int d0 = blockIdx.x * 64;
        #pragma unroll
        for (int p = 0; p < 4; p++) {
            int dd = p * 16 + (t >> 4), i4 = (t & 15) * 4;
            float4 v = *(const float4*)&Wc[((size_t)l * D_DIM + d0 + dd) * I_DIM + i4];
            tile[dd][i4] = v.x; tile[dd][i4+1] = v.y; tile[dd][i4+2] = v.z; tile[dd][i4+3] = v.w;
        }
        __syncthreads();
        #pragma unroll
        for (int p = 0; p < 4; p++) {
            int i = p * 16 + (t >> 4), dd0 = (t & 15) * 4;
            u16 h[4], lo[4];
            #pragma unroll
            for (int j = 0; j < 4; j++) split2(tile[dd0 + j][i], h[j], lo[j]);
            size_t base = ((size_t)l * I_DIM + i) * D_DIM + d0 + dd0;
            uint2 ph; ph.x = h[0] | ((unsigned)h[1] << 16); ph.y = h[2] | ((unsigned)h[3] << 16);
            uint2 pl; pl.x = lo[0] | ((unsigned)lo[1] << 16); pl.y = lo[2] | ((unsigned)lo[3] << 16);
            *(uint2*)&cH[base] = ph;
            *(uint2*)&cL[base] = pl;
        }
    } else {
        const int k = blockIdx.x - 12;
        #pragma unroll
        for (int p = 0; p < 4; p++) {
            int i = p * 16 + (t >> 4), o4 = (t & 15) * 4;
            float4 v = *(const float4*)&Wv[(((size_t)l * K_DIM + k) * I_DIM + i) * O_DIM + o4];
            tile[i][o4] = v.x; tile[i][o4+1] = v.y; tile[i][o4+2] = v.z; tile[i][o4+3] = v.w;
        }
        __syncthreads();
        #pragma unroll
        for (int p = 0; p < 4; p++) {
            int o = p * 16 + (t >> 4), i0 = (t & 15) * 4;
            u16 h[4], lo[4];
            #pragma unroll
            for (int j = 0; j < 4; j++) split2(tile[i0 + j][o], h[j], lo[j]);
            size_t base = (((size_t)l * K_DIM + k) * O_DIM + o) * I_DIM + i0;
            uint2 ph; ph.x = h[0] | ((unsigned)h[1] << 16); ph.y = h[2] | ((unsigned)h[3] << 16);
            uint2 pl; pl.x = lo[0] | ((unsigned)lo[1] << 16); pl.y = lo[2] | ((unsigned)lo[3] << 16);
            *(uint2*)&vH[base] = ph;
            *(uint2*)&vL[base] = pl;
        }
    }
}

// ---------------------------------------------------------------------------
// Kernel A v7: 16-n tile, ALL of D staged once (55 KB LDS), barrier-free
// MFMA phase. Each thread issues its 12 x-loads back-to-back (one HBM
// round-trip for the whole staging, not 12 coupled ones); after ONE barrier
// the 4 waves run 24 k-steps x 3 MFMA fully independently (no sync coupling,
// W-frags stream from XCD-local L2). grid (nchunk/16, 32), 256 thr,
// 2 blocks/CU (LDS-limited).
// ---------------------------------------------------------------------------
__global__ __launch_bounds__(256, 2) void kernelA(
    const float* __restrict__ x, const float* __restrict__ mask,
    const float* __restrict__ Wscore, const float* __restrict__ Bscore,
    const u16* __restrict__ WcH, const u16* __restrict__ WcL,
    const float* __restrict__ Bcap,
    float* __restrict__ mu_out, float* __restrict__ fa_out,
    int nbase, int nchunk)
{
    // XCD-locality swizzle (bijective): each XCD sees 4 layers' weights.
    const int bid  = blockIdx.y * gridDim.x + blockIdx.x;
    const int slot = bid >> 3;
    const int l    = (bid & 7) + 8 * (slot & 3);
    const int n0l  = (slot >> 2) * 16;

    const int t    = threadIdx.x;
    const int w    = t >> 6;
    const int lane = t & 63;
    const int quad = lane >> 4;
    const int ln16 = lane & 15;

    __shared__ u16 xh[12][16][PX], xl[12][16][PX];   // 55.3 KB
    __shared__ float wsc_s[D_DIM];                    // 3 KB
    __shared__ float bcap_s[64];

    for (int i = t; i < D_DIM; i += 256) wsc_s[i] = Wscore[l * D_DIM + i];
    if (t < 64) bcap_s[t] = Bcap[l * I_DIM + t];

    const int sg = t >> 4;          // staging row 0..15
    const int sd = (t & 15) * 4;    // staging col offset

    const size_t xoff = ((size_t)(nbase + n0l + sg) * L_DIM + l) * D_DIM;

    // issue ALL x loads up front (independent float4 regs -> deep MLP)
    float4 xr[12];
    #pragma unroll
    for (int ch = 0; ch < 12; ch++)
        xr[ch] = *(const float4*)&x[xoff + ch * 64 + sd];

    __syncthreads();   // wsc_s ready

    float fa = 0.f;
    #pragma unroll
    for (int ch = 0; ch < 12; ch++) {
        const float* wp = &wsc_s[ch * 64 + sd];
        fa += xr[ch].x * wp[0] + xr[ch].y * wp[1] + xr[ch].z * wp[2] + xr[ch].w * wp[3];
        store_split4(&xh[ch][sg][sd], &xl[ch][sg][sd], xr[ch]);
    }

    // fa reduce over the 16 lanes sharing a row
    fa += __shfl_xor(fa, 1, 64);
    fa += __shfl_xor(fa, 2, 64);
    fa += __shfl_xor(fa, 4, 64);
    fa += __shfl_xor(fa, 8, 64);
    if ((t & 15) == 0) {
        float a = fa + Bscore[l];
        float sig = 1.f / (1.f + expf(-a));
        float m = mask[(size_t)(nbase + n0l + sg) * L_DIM + l];
        fa_out[(size_t)l * nchunk + n0l + sg] = sig * m;
    }

    __syncthreads();   // x tiles ready; no further barriers

    const size_t wrow = ((size_t)l * I_DIM + (w * 16 + ln16)) * D_DIM + quad * 8;
    f32x4 acc = {0.f, 0.f, 0.f, 0.f};
    #pragma unroll
    for (int ch = 0; ch < 12; ch++) {
        #pragma unroll
        for (int ks = 0; ks < 2; ks++) {
            const int kk = ks * 32;
            short8 ah = *(const short8*)&WcH[wrow + ch * 64 + kk];
            short8 al = *(const short8*)&WcL[wrow + ch * 64 + kk];
            short8 bh = *(const short8*)&xh[ch][ln16][kk + quad * 8];
            short8 bl = *(const short8*)&xl[ch][ln16][kk + quad * 8];
            acc = MFMA(ah, bh, acc, 0, 0, 0);
            acc = MFMA(ah, bl, acc, 0, 0, 0);
            acc = MFMA(al, bh, acc, 0, 0, 0);
        }
    }

    // epilogue: D row i = w*16 + quad*4 + r; col n = ln16
    const int i0 = w * 16 + quad * 4;
    float4 o;
    float* op = (float*)&o;
    #pragma unroll
    for (int r = 0; r < 4; r++) {
        float v = acc[r] + bcap_s[i0 + r];
        op[r] = 0.5f * v * (1.f + erff(v * 0.70710678118f));
    }
    *(float4*)&mu_out[((size_t)l * nchunk + n0l + ln16) * I_DIM + i0] = o;
}

// ---------------------------------------------------------------------------
// Kernel B (REVERTED to the R3 version — the best-measured total's B).
// V[l][k][n][o] = mu·Wvote + Bvote. grid (nchunk/64,16,32), 8192 blocks.
// (B v6's 4-k grouping finished so fast it shifted V's 100+ MB writeback
// into kernelC's window and evicted V before C read it: C FETCH 66->128MB.)
// ---------------------------------------------------------------------------
__global__ __launch_bounds__(256) void kernelB(
    const float* __restrict__ mu_in,
    const u16* __restrict__ WvH, const u16* __restrict__ WvL,
    const float* __restrict__ Bvote,
    float* __restrict__ V, int nchunk)
{
    const int bid  = (blockIdx.z * gridDim.y + blockIdx.y) * gridDim.x + blockIdx.x;
    const int slot = bid >> 3;
    const int l    = (bid & 7) + 8 * (slot & 3);
    const int rem  = slot >> 2;
    const int k    = rem & 15;
    const int n0l  = (rem >> 4) * 64;

    const int t    = threadIdx.x;
    const int w    = t >> 6;
    const int lane = t & 63;
    const int quad = lane >> 4;
    const int ln16 = lane & 15;

    __shared__ u16 mh[64][PX], ml[64][PX];
    __shared__ float bvote_s[64];

    const int srow = t >> 4, scol = (t & 15) * 4;
    float4 m0 = *(const float4*)&mu_in[((size_t)l * nchunk + n0l + srow) * I_DIM + scol];
    float4 m1 = *(const float4*)&mu_in[((size_t)l * nchunk + n0l + 16 + srow) * I_DIM + scol];
    float4 m2 = *(const float4*)&mu_in[((size_t)l * nchunk + n0l + 32 + srow) * I_DIM + scol];
    float4 m3 = *(const float4*)&mu_in[((size_t)l * nchunk + n0l + 48 + srow) * I_DIM + scol];

    const size_t wrow = (((size_t)l * K_DIM + k) * O_DIM + (w * 16 + ln16)) * I_DIM + quad * 8;
    short8 ah0 = *(const short8*)&WvH[wrow];
    short8 al0 = *(const short8*)&WvL[wrow];
    short8 ah1 = *(const short8*)&WvH[wrow + 32];
    short8 al1 = *(const short8*)&WvL[wrow + 32];

    if (t < 64) bvote_s[t] = Bvote[((size_t)l * K_DIM + k) * O_DIM + t];

    store_split4(&mh[srow][scol],      &ml[srow][scol],      m0);
    store_split4(&mh[16 + srow][scol], &ml[16 + srow][scol], m1);
    store_split4(&mh[32 + srow][scol], &ml[32 + srow][scol], m2);
    store_split4(&mh[48 + srow][scol], &ml[48 + srow][scol], m3);
    __syncthreads();

    f32x4 acc[4] = {{0.f,0.f,0.f,0.f},{0.f,0.f,0.f,0.f},{0.f,0.f,0.f,0.f},{0.f,0.f,0.f,0.f}};

    #pragma unroll
    for (int c = 0; c < 4; c++) {
        const int n = c * 16 + ln16;
        short8 bh = *(const short8*)&mh[n][quad * 8];
        short8 bl = *(const short8*)&ml[n][quad * 8];
        acc[c] = MFMA(ah0, bh, acc[c], 0, 0, 0);
        acc[c] = MFMA(ah0, bl, acc[c], 0, 0, 0);
        acc[c] = MFMA(al0, bh, acc[c], 0, 0, 0);
    }
    #pragma unroll
    for (int c = 0; c < 4; c++) {
        const int n = c * 16 + ln16;
        short8 bh = *(const short8*)&mh[n][32 + quad * 8];
        short8 bl = *(const short8*)&ml[n][32 + quad * 8];
        acc[c] = MFMA(ah1, bh, acc[c], 0, 0, 0);
        acc[c] = MFMA(ah1, bl, acc[c], 0, 0, 0);
        acc[c] = MFMA(al1, bh, acc[c], 0, 0, 0);
    }

    #pragma unroll
    for (int c = 0; c < 4; c++) {
        const int n = c * 16 + ln16;
        const int o0 = w * 16 + quad * 4;
        float4 o;
        o.x = acc[c][0] + bvote_s[o0];
        o.y = acc[c][1] + bvote_s[o0 + 1];
        o.z = acc[c][2] + bvote_s[o0 + 2];
        o.w = acc[c][3] + bvote_s[o0 + 3];
        *(float4*)&V[(((size_t)l * K_DIM + k) * nchunk + n0l + n) * O_DIM + o0] = o;
    }
}

// ---------------------------------------------------------------------------
// Kernel C (unchanged from round 6): EM routing, one block per n, 512 thr.
// V[l][k][n][o]; Rfa/RfaBu b128 M-step, Sfa identity, 62-shfl fold E-step.
// ---------------------------------------------------------------------------
__global__ __launch_bounds__(512, 4) void kernelC(
    const float* __restrict__ V, const float* __restrict__ fa_in,
    const float* __restrict__ beta_use, const float* __restrict__ beta_ign,
    const int* __restrict__ iters_p,
    float* __restrict__ out, int nbase, int nchunk)
{
    const int nl   = blockIdx.x;
    const int ng   = nbase + nl;
    const int t    = threadIdx.x;     // 0..511
    const int k    = t >> 5;          // capsule, one per 32-lane half-wave
    const int op   = t & 31;          // o-pair index
    const int o0   = op * 2;
    const int lane = t & 63;
    int iters = iters_p[0];
    if (iters < 0 || iters > 16) iters = 3;

    __shared__ float sc_s[32][17];
    __shared__ float Rfa_s[16][36];
    __shared__ float RfaBu_s[16][36];

    // V[l][k][n][o]: per l, each half-wave reads 32 consecutive float2
    float2 Vr[32];
    #pragma unroll
    for (int l = 0; l < 32; l++)
        Vr[l] = *(const float2*)&V[(((size_t)l * K_DIM + k) * nchunk + nl) * O_DIM + o0];

    // per-thread scalars (L2-broadcast loads)
    const int lrow = t >> 4;          // 0..31 : softmax/init row
    const int kcol = t & 15;          // 0..15 : softmax/init col
    const float fa_l = fa_in[(size_t)lrow * nchunk + nl];
    const float bu_l = beta_use[lrow];
    const float bi_k = beta_ign[k];

    // init Rfa/RfaBu for R = 1/16 (thread (lrow,kcol) owns one cell)
    Rfa_s[kcol][lrow]   = fa_l * (1.f / 16.f);
    RfaBu_s[kcol][lrow] = fa_l * bu_l * (1.f / 16.f);
    __syncthreads();

    float mu0 = 0.f, mu1 = 0.f, var0 = 0.f, var1 = 0.f, a_r = 0.f;
    float Sfa = 0.f;

    for (int it = 0; it < iters; it++) {
        if (it > 0) {
            float g0 = 1.f / (2.f * var0 + EPSF);
            float g1 = 1.f / (2.f * var1 + EPSF);
            float lvp = logf(var0 + EPSF) + logf(var1 + EPSF);
            lvp += __shfl_xor(lvp, 1, 64);
            lvp += __shfl_xor(lvp, 2, 64);
            lvp += __shfl_xor(lvp, 4, 64);
            lvp += __shfl_xor(lvp, 8, 64);
            lvp += __shfl_xor(lvp, 16, 64);
            float ls = fminf(a_r, 0.f) - log1pf(expf(-fabsf(a_r)));
            const float cst = ls - 1.f - 1.57079632679f - 0.5f * lvp;

            // ---- fold: 32 per-l partials over 32 lanes, 62 shfls total ----
            const bool s16 = (lane & 16) != 0;
            const bool s8  = (lane & 8)  != 0;
            const bool s4  = (lane & 4)  != 0;
            const bool s2  = (lane & 2)  != 0;
            const bool s1  = (lane & 1)  != 0;
            float w16[16];
            #pragma unroll
            for (int j = 0; j < 16; j++) {
                float d0 = Vr[j].x - mu0,      d1 = Vr[j].y - mu1;
                float a  = d0 * d0 * g0 + d1 * d1 * g1;
                float e0 = Vr[j + 16].x - mu0, e1 = Vr[j + 16].y - mu1;
                float b  = e0 * e0 * g0 + e1 * e1 * g1;
                float ta = a + __shfl_xor(a, 16, 64);
                float tb = b + __shfl_xor(b, 16, 64);
                w16[j] = s16 ? tb : ta;
            }
            float w8[8];
            #pragma unroll
            for (int j = 0; j < 8; j++) {
                float ta = w16[j]     + __shfl_xor(w16[j],     8, 64);
                float tb = w16[j + 8] + __shfl_xor(w16[j + 8], 8, 64);
                w8[j] = s8 ? tb : ta;
            }
            float w4[4];
            #pragma unroll
            for (int j = 0; j < 4; j++) {
                float ta = w8[j]     + __shfl_xor(w8[j],     4, 64);
                float tb = w8[j + 4] + __shfl_xor(w8[j + 4], 4, 64);
                w4[j] = s4 ? tb : ta;
            }
            float w2[2];
            #pragma unroll
            for (int j = 0; j < 2; j++) {
                float ta = w4[j]     + __shfl_xor(w4[j],     2, 64);
                float tb = w4[j + 2] + __shfl_xor(w4[j + 2], 2, 64);
                w2[j] = s2 ? tb : ta;
            }
            float ta = w2[0] + __shfl_xor(w2[0], 1, 64);
            float tb = w2[1] + __shfl_xor(w2[1], 1, 64);
            float w1 = s1 ? tb : ta;
            sc_s[lane & 31][k] = cst - w1;
            __syncthreads();

            {   // softmax over k: thread (lrow, kcol); writes Rfa/RfaBu
                float s0 = sc_s[lrow][kcol];
                float m = s0;
                m = fmaxf(m, __shfl_xor(m, 1, 64));
                m = fmaxf(m, __shfl_xor(m, 2, 64));
                m = fmaxf(m, __shfl_xor(m, 4, 64));
                m = fmaxf(m, __shfl_xor(m, 8, 64));
                float e = expf(s0 - m);
                float sum = e;
                sum += __shfl_xor(sum, 1, 64);
                sum += __shfl_xor(sum, 2, 64);
                sum += __shfl_xor(sum, 4, 64);
                sum += __shfl_xor(sum, 8, 64);
                float R = e / sum;
                float rf = R * fa_l;
                Rfa_s[kcol][lrow]   = rf;
                RfaBu_s[kcol][lrow] = rf * bu_l;
            }
            __syncthreads();
        }
        // M-step: 16 broadcast b128 reads per thread
        float denom = EPSF, sbu = 0.f;
        float mua0 = 0.f, mua1 = 0.f, v2a0 = 0.f, v2a1 = 0.f;
        #pragma unroll
        for (int l4 = 0; l4 < 8; l4++) {
            const float4 rf = *(const float4*)&Rfa_s[k][l4 * 4];
            const float4 rb = *(const float4*)&RfaBu_s[k][l4 * 4];
            const float* rfp = (const float*)&rf;
            const float* rbp = (const float*)&rb;
            #pragma unroll
            for (int j = 0; j < 4; j++) {
                const int l = l4 * 4 + j;
                float Du = rfp[j];
                denom += Du;
                sbu   += rbp[j];
                float dv0 = Du * Vr[l].x;
                float dv1 = Du * Vr[l].y;
                mua0 += dv0;  v2a0 += dv0 * Vr[l].x;
                mua1 += dv1;  v2a1 += dv1 * Vr[l].y;
            }
        }
        if (it == 0) Sfa = (denom - EPSF) * 16.f;
        a_r = sbu + bi_k * ((denom - EPSF) - Sfa);
        float invd = 1.f / denom;
        mu0 = mua0 * invd;
        mu1 = mua1 * invd;
        var0 = fmaxf(v2a0 * invd - mu0 * mu0, 0.f);
        var1 = fmaxf(v2a1 * invd - mu1 * mu1, 0.f);
    }

    if (op == 0) out[(size_t)ng * K_DIM + k] = a_r;
    float2 o2; o2.x = mu0; o2.y = mu1;
    *(float2*)&out[(size_t)N_DIM * K_DIM + ((size_t)ng * K_DIM + k) * O_DIM + o0] = o2;
}

extern "C" void kernel_launch(void* const* d_in, const int* in_sizes, int n_in,
                              void* d_out, int out_size, void* d_ws, size_t ws_size,
                              hipStream_t stream) {
    (void)out_size;
    static const int EXP[11] = {25165824, 32768, 24576, 32, 1572864, 64,
                                2097152, 65536, 32, 16, 1};
    int mapi[11];
    bool used[64] = {false};
    for (int s = 0; s < 11; s++) {
        mapi[s] = (s < n_in) ? s : 0;
        for (int j = 0; j < n_in && j < 64; j++) {
            if (!used[j] && in_sizes[j] == EXP[s]) { mapi[s] = j; used[j] = true; break; }
        }
    }
    const float* x        = (const float*)d_in[mapi[0]];
    const float* mask     = (const float*)d_in[mapi[1]];
    const float* Wscore   = (const float*)d_in[mapi[2]];
    const float* Bscore   = (const float*)d_in[mapi[3]];
    const float* Wcap     = (const float*)d_in[mapi[4]];
    const float* Bcap     = (const float*)d_in[mapi[5]];
    const float* Wvote    = (const float*)d_in[mapi[6]];
    const float* Bvote    = (const float*)d_in[mapi[7]];
    const float* beta_use = (const float*)d_in[mapi[8]];
    const float* beta_ign = (const float*)d_in[mapi[9]];
    const int*   iters    = (const int*)d_in[mapi[10]];
    float* out = (float*)d_out;

    const size_t WCAP = (size_t)L_DIM * I_DIM * D_DIM;         // u16 elems
    const size_t WVOT = (size_t)L_DIM * K_DIM * O_DIM * I_DIM; // u16 elems
    const size_t WBYTES = 2 * WCAP * 2 + 2 * WVOT * 2;

    int C = 64;
    {
        const int cands[5] = {1024, 512, 256, 128, 64};
        for (int i = 0; i < 5; i++) {
            size_t need = WBYTES + (size_t)cands[i] * (128 + 8192 + 131072);
            if (need <= ws_size) { C = cands[i]; break; }
        }
    }

    char* ws = (char*)d_ws;
    u16* WcH = (u16*)ws;
    u16* WcL = (u16*)(ws + WCAP * 2);
    u16* WvH = (u16*)(ws + WCAP * 4);
    u16* WvL = (u16*)(ws + WCAP * 4 + WVOT * 2);
    char* dyn = ws + WBYTES;
    float* fa = (float*)dyn;
    float* mu = (float*)(dyn + (size_t)128 * C);
    float* V  = (float*)(dyn + (size_t)128 * C + (size_t)8192 * C);

    prep_w<<<dim3(28, 32), 256, 0, stream>>>(Wcap, WcH, WcL, Wvote, WvH, WvL);

    for (int nbase = 0; nbase < N_DIM; nbase += C) {
        kernelA<<<dim3(C / 16, 32), 256, 0, stream>>>(
            x, mask, Wscore, Bscore, WcH, WcL, Bcap, mu, fa, nbase, C);
        kernelB<<<dim3(C / 64, 16, 32), 256, 0, stream>>>(
            mu, WvH, WvL, Bvote, V, C);
        kernelC<<<dim3(C), 512, 0, stream>>>(
            V, fa, beta_use, beta_ign, iters, out, nbase, C);
    }
}

// Round 8
// 265.507 us; speedup vs baseline: 1.2585x; 1.2585x over previous
//
#include <hip/hip_runtime.h>
#include <hip/hip_bf16.h>

#define L_DIM 32
#define N_DIM 1024
#define D_DIM 768
#define K_DIM 16
#define I_DIM 64
#define O_DIM 64
#define EPSF 1e-8f
#define PX 72   // padded LDS row (bf16 elems): 144 B

typedef unsigned short u16;
typedef __attribute__((ext_vector_type(8))) short short8;   // 8 bf16 (4 VGPRs)
typedef __attribute__((ext_vector_type(4))) float f32x4;
#define MFMA __builtin_amdgcn_mfma_f32_16x16x32_bf16

__device__ __forceinline__ float bf2f(u16 v) {
    union { unsigned int u; float f; } x; x.u = ((unsigned int)v) << 16; return x.f;
}
__device__ __forceinline__ u16 f2bf(float f) {
    union { float f; unsigned int u; } x; x.f = f;
    unsigned int u = x.u;
    u += 0x7FFFu + ((u >> 16) & 1u);   // RNE
    return (u16)(u >> 16);
}
__device__ __forceinline__ void split2(float v, u16& h, u16& l) {
    u16 hh = f2bf(v);
    h = hh;
    l = f2bf(v - bf2f(hh));
}
// cheap truncation split of float4 -> packed hi uint2 + lo uint2 (exact residual)
__device__ __forceinline__ void store_split4(u16* ph, u16* pl, float4 v) {
    unsigned u0 = __float_as_uint(v.x), u1 = __float_as_uint(v.y);
    unsigned u2 = __float_as_uint(v.z), u3 = __float_as_uint(v.w);
    uint2 H, L;
    H.x = (u0 >> 16) | (u1 & 0xFFFF0000u);
    H.y = (u2 >> 16) | (u3 & 0xFFFF0000u);
    float l0 = v.x - __uint_as_float(u0 & 0xFFFF0000u);
    float l1 = v.y - __uint_as_float(u1 & 0xFFFF0000u);
    float l2 = v.z - __uint_as_float(u2 & 0xFFFF0000u);
    float l3 = v.w - __uint_as_float(u3 & 0xFFFF0000u);
    L.x = (__float_as_uint(l0) >> 16) | (__float_as_uint(l1) & 0xFFFF0000u);
    L.y = (__float_as_uint(l2) >> 16) | (__float_as_uint(l3) & 0xFFFF0000u);
    *(uint2*)ph = H;
    *(uint2*)pl = L;
}

// ---------------------------------------------------------------------------
// Prep (merged): blockIdx.x < 12 -> Wcap [l][d][i] -> [l][i][d] hi/lo
//                blockIdx.x >= 12 -> Wvote [l][k][i][o] -> [l][k][o][i] hi/lo
// grid (28, 32), 256 thr. Branch is block-uniform.
// ---------------------------------------------------------------------------
__global__ __launch_bounds__(256) void prep_w(
    const float* __restrict__ Wc, u16* __restrict__ cH, u16* __restrict__ cL,
    const float* __restrict__ Wv, u16* __restrict__ vH, u16* __restrict__ vL)
{
    const int l = blockIdx.y, t = threadIdx.x;
    __shared__ float tile[64][65];
    if (blockIdx.x < 12) {
        const int d0 = blockIdx.x * 64;
        #pragma unroll
        for (int p = 0; p < 4; p++) {
            int dd = p * 16 + (t >> 4), i4 = (t & 15) * 4;
            float4 v = *(const float4*)&Wc[((size_t)l * D_DIM + d0 + dd) * I_DIM + i4];
            tile[dd][i4] = v.x; tile[dd][i4+1] = v.y; tile[dd][i4+2] = v.z; tile[dd][i4+3] = v.w;
        }
        __syncthreads();
        #pragma unroll
        for (int p = 0; p < 4; p++) {
            int i = p * 16 + (t >> 4), dd0 = (t & 15) * 4;
            u16 h[4], lo[4];
            #pragma unroll
            for (int j = 0; j < 4; j++) split2(tile[dd0 + j][i], h[j], lo[j]);
            size_t base = ((size_t)l * I_DIM + i) * D_DIM + d0 + dd0;
            uint2 ph; ph.x = h[0] | ((unsigned)h[1] << 16); ph.y = h[2] | ((unsigned)h[3] << 16);
            uint2 pl; pl.x = lo[0] | ((unsigned)lo[1] << 16); pl.y = lo[2] | ((unsigned)lo[3] << 16);
            *(uint2*)&cH[base] = ph;
            *(uint2*)&cL[base] = pl;
        }
    } else {
        const int k = blockIdx.x - 12;
        #pragma unroll
        for (int p = 0; p < 4; p++) {
            int i = p * 16 + (t >> 4), o4 = (t & 15) * 4;
            float4 v = *(const float4*)&Wv[(((size_t)l * K_DIM + k) * I_DIM + i) * O_DIM + o4];
            tile[i][o4] = v.x; tile[i][o4+1] = v.y; tile[i][o4+2] = v.z; tile[i][o4+3] = v.w;
        }
        __syncthreads();
        #pragma unroll
        for (int p = 0; p < 4; p++) {
            int o = p * 16 + (t >> 4), i0 = (t & 15) * 4;
            u16 h[4], lo[4];
            #pragma unroll
            for (int j = 0; j < 4; j++) split2(tile[i0 + j][o], h[j], lo[j]);
            size_t base = (((size_t)l * K_DIM + k) * O_DIM + o) * I_DIM + i0;
            uint2 ph; ph.x = h[0] | ((unsigned)h[1] << 16); ph.y = h[2] | ((unsigned)h[3] << 16);
            uint2 pl; pl.x = lo[0] | ((unsigned)lo[1] << 16); pl.y = lo[2] | ((unsigned)lo[3] << 16);
            *(uint2*)&vH[base] = ph;
            *(uint2*)&vL[base] = pl;
        }
    }
}

// ---------------------------------------------------------------------------
// Kernel A (RESTORED round-1 version — best measured A):
// MFMA, 32-n tile, depth-2 reg pipeline for x AND weights, 1 barrier/chunk,
// XCD-swizzled block mapping. (A v7's all-of-D staging regressed to 83 us:
// 2 blocks/CU + L2-latency-bound weight stream.)
// ---------------------------------------------------------------------------
#define A_CHUNK(K0, R0, R1, WH0, WL0, WH1, WL1, BUF)                        \
  {                                                                          \
    const float* wp = &wsc_s[(K0) + sd];                                     \
    fa0 += R0.x * wp[0] + R0.y * wp[1] + R0.z * wp[2] + R0.w * wp[3];        \
    fa1 += R1.x * wp[0] + R1.y * wp[1] + R1.z * wp[2] + R1.w * wp[3];        \
    store_split4(&xh[BUF][sg][sd],      &xl[BUF][sg][sd],      R0);          \
    store_split4(&xh[BUF][16 + sg][sd], &xl[BUF][16 + sg][sd], R1);          \
    __syncthreads();                                                         \
    if ((K0) + 128 < D_DIM) {                                                \
      R0 = *(const float4*)&x[xoff0 + (K0) + 128 + sd];                      \
      R1 = *(const float4*)&x[xoff1 + (K0) + 128 + sd];                      \
    }                                                                        \
    {                                                                        \
      short8 bh, bl;                                                         \
      bh = *(const short8*)&xh[BUF][ln16][quad * 8];                         \
      bl = *(const short8*)&xl[BUF][ln16][quad * 8];                         \
      acc0 = MFMA(WH0, bh, acc0, 0, 0, 0);                                   \
      acc0 = MFMA(WH0, bl, acc0, 0, 0, 0);                                   \
      acc0 = MFMA(WL0, bh, acc0, 0, 0, 0);                                   \
      bh = *(const short8*)&xh[BUF][16 + ln16][quad * 8];                    \
      bl = *(const short8*)&xl[BUF][16 + ln16][quad * 8];                    \
      acc1 = MFMA(WH0, bh, acc1, 0, 0, 0);                                   \
      acc1 = MFMA(WH0, bl, acc1, 0, 0, 0);                                   \
      acc1 = MFMA(WL0, bh, acc1, 0, 0, 0);                                   \
      bh = *(const short8*)&xh[BUF][ln16][32 + quad * 8];                    \
      bl = *(const short8*)&xl[BUF][ln16][32 + quad * 8];                    \
      acc0 = MFMA(WH1, bh, acc0, 0, 0, 0);                                   \
      acc0 = MFMA(WH1, bl, acc0, 0, 0, 0);                                   \
      acc0 = MFMA(WL1, bh, acc0, 0, 0, 0);                                   \
      bh = *(const short8*)&xh[BUF][16 + ln16][32 + quad * 8];               \
      bl = *(const short8*)&xl[BUF][16 + ln16][32 + quad * 8];               \
      acc1 = MFMA(WH1, bh, acc1, 0, 0, 0);                                   \
      acc1 = MFMA(WH1, bl, acc1, 0, 0, 0);                                   \
      acc1 = MFMA(WL1, bh, acc1, 0, 0, 0);                                   \
    }                                                                        \
    if ((K0) + 128 < D_DIM) {                                                \
      WH0 = *(const short8*)&WcH[wrow + (K0) + 128];                         \
      WL0 = *(const short8*)&WcL[wrow + (K0) + 128];                         \
      WH1 = *(const short8*)&WcH[wrow + (K0) + 160];                         \
      WL1 = *(const short8*)&WcL[wrow + (K0) + 160];                         \
    }                                                                        \
  }

__global__ __launch_bounds__(256, 4) void kernelA(
    const float* __restrict__ x, const float* __restrict__ mask,
    const float* __restrict__ Wscore, const float* __restrict__ Bscore,
    const u16* __restrict__ WcH, const u16* __restrict__ WcL,
    const float* __restrict__ Bcap,
    float* __restrict__ mu_out, float* __restrict__ fa_out,
    int nbase, int nchunk)
{
    const int bid  = blockIdx.y * gridDim.x + blockIdx.x;
    const int slot = bid >> 3;
    const int l    = (bid & 7) + 8 * (slot & 3);
    const int n0l  = (slot >> 2) * 32;

    const int t    = threadIdx.x;
    const int w    = t >> 6;
    const int lane = t & 63;
    const int quad = lane >> 4;
    const int ln16 = lane & 15;

    __shared__ u16 xh[2][32][PX], xl[2][32][PX];
    __shared__ float wsc_s[D_DIM];
    __shared__ float bcap_s[64];

    for (int i = t; i < D_DIM; i += 256) wsc_s[i] = Wscore[l * D_DIM + i];
    if (t < 64) bcap_s[t] = Bcap[l * I_DIM + t];

    const int sg = t >> 4;          // staging row group 0..15
    const int sd = (t & 15) * 4;    // staging col offset

    const size_t xoff0 = ((size_t)(nbase + n0l + sg) * L_DIM + l) * D_DIM;
    const size_t xoff1 = ((size_t)(nbase + n0l + 16 + sg) * L_DIM + l) * D_DIM;

    float4 r0a = *(const float4*)&x[xoff0 + sd];
    float4 r1a = *(const float4*)&x[xoff1 + sd];
    float4 r0b = *(const float4*)&x[xoff0 + 64 + sd];
    float4 r1b = *(const float4*)&x[xoff1 + 64 + sd];

    const size_t wrow = ((size_t)l * I_DIM + (w * 16 + ln16)) * D_DIM + quad * 8;
    short8 wha0 = *(const short8*)&WcH[wrow];
    short8 wla0 = *(const short8*)&WcL[wrow];
    short8 wha1 = *(const short8*)&WcH[wrow + 32];
    short8 wla1 = *(const short8*)&WcL[wrow + 32];
    short8 whb0 = *(const short8*)&WcH[wrow + 64];
    short8 wlb0 = *(const short8*)&WcL[wrow + 64];
    short8 whb1 = *(const short8*)&WcH[wrow + 96];
    short8 wlb1 = *(const short8*)&WcL[wrow + 96];

    __syncthreads();   // wsc_s / bcap_s ready

    f32x4 acc0 = {0.f, 0.f, 0.f, 0.f};
    f32x4 acc1 = {0.f, 0.f, 0.f, 0.f};
    float fa0 = 0.f, fa1 = 0.f;

    #pragma unroll
    for (int cc = 0; cc < 6; cc++) {
        A_CHUNK(cc * 128,      r0a, r1a, wha0, wla0, wha1, wla1, 0)
        A_CHUNK(cc * 128 + 64, r0b, r1b, whb0, wlb0, whb1, wlb1, 1)
    }

    fa0 += __shfl_xor(fa0, 1, 64); fa1 += __shfl_xor(fa1, 1, 64);
    fa0 += __shfl_xor(fa0, 2, 64); fa1 += __shfl_xor(fa1, 2, 64);
    fa0 += __shfl_xor(fa0, 4, 64); fa1 += __shfl_xor(fa1, 4, 64);
    fa0 += __shfl_xor(fa0, 8, 64); fa1 += __shfl_xor(fa1, 8, 64);
    if ((t & 15) == 0) {
        float bs = Bscore[l];
        {
            float a = fa0 + bs;
            float sig = 1.f / (1.f + expf(-a));
            float m = mask[(size_t)(nbase + n0l + sg) * L_DIM + l];
            fa_out[(size_t)l * nchunk + n0l + sg] = sig * m;
        }
        {
            float a = fa1 + bs;
            float sig = 1.f / (1.f + expf(-a));
            float m = mask[(size_t)(nbase + n0l + 16 + sg) * L_DIM + l];
            fa_out[(size_t)l * nchunk + n0l + 16 + sg] = sig * m;
        }
    }

    #pragma unroll
    for (int c = 0; c < 2; c++) {
        const f32x4 a = (c == 0) ? acc0 : acc1;
        const int n = c * 16 + ln16;
        const int i0 = w * 16 + quad * 4;
        float4 o;
        float* op = (float*)&o;
        #pragma unroll
        for (int r = 0; r < 4; r++) {
            float v = a[r] + bcap_s[i0 + r];
            op[r] = 0.5f * v * (1.f + erff(v * 0.70710678118f));
        }
        *(float4*)&mu_out[((size_t)l * nchunk + n0l + n) * I_DIM + i0] = o;
    }
}

// ---------------------------------------------------------------------------
// Kernel B (R1/R3 version): V[l][k][n][o] = mu·Wvote + Bvote (f32).
// grid (nchunk/64,16,32). XCD-swizzled.
// ---------------------------------------------------------------------------
__global__ __launch_bounds__(256) void kernelB(
    const float* __restrict__ mu_in,
    const u16* __restrict__ WvH, const u16* __restrict__ WvL,
    const float* __restrict__ Bvote,
    float* __restrict__ V, int nchunk)
{
    const int bid  = (blockIdx.z * gridDim.y + blockIdx.y) * gridDim.x + blockIdx.x;
    const int slot = bid >> 3;
    const int l    = (bid & 7) + 8 * (slot & 3);
    const int rem  = slot >> 2;
    const int k    = rem & 15;
    const int n0l  = (rem >> 4) * 64;

    const int t    = threadIdx.x;
    const int w    = t >> 6;
    const int lane = t & 63;
    const int quad = lane >> 4;
    const int ln16 = lane & 15;

    __shared__ u16 mh[64][PX], ml[64][PX];
    __shared__ float bvote_s[64];

    const int srow = t >> 4, scol = (t & 15) * 4;
    float4 m0 = *(const float4*)&mu_in[((size_t)l * nchunk + n0l + srow) * I_DIM + scol];
    float4 m1 = *(const float4*)&mu_in[((size_t)l * nchunk + n0l + 16 + srow) * I_DIM + scol];
    float4 m2 = *(const float4*)&mu_in[((size_t)l * nchunk + n0l + 32 + srow) * I_DIM + scol];
    float4 m3 = *(const float4*)&mu_in[((size_t)l * nchunk + n0l + 48 + srow) * I_DIM + scol];

    const size_t wrow = (((size_t)l * K_DIM + k) * O_DIM + (w * 16 + ln16)) * I_DIM + quad * 8;
    short8 ah0 = *(const short8*)&WvH[wrow];
    short8 al0 = *(const short8*)&WvL[wrow];
    short8 ah1 = *(const short8*)&WvH[wrow + 32];
    short8 al1 = *(const short8*)&WvL[wrow + 32];

    if (t < 64) bvote_s[t] = Bvote[((size_t)l * K_DIM + k) * O_DIM + t];

    store_split4(&mh[srow][scol],      &ml[srow][scol],      m0);
    store_split4(&mh[16 + srow][scol], &ml[16 + srow][scol], m1);
    store_split4(&mh[32 + srow][scol], &ml[32 + srow][scol], m2);
    store_split4(&mh[48 + srow][scol], &ml[48 + srow][scol], m3);
    __syncthreads();

    f32x4 acc[4] = {{0.f,0.f,0.f,0.f},{0.f,0.f,0.f,0.f},{0.f,0.f,0.f,0.f},{0.f,0.f,0.f,0.f}};

    #pragma unroll
    for (int c = 0; c < 4; c++) {
        const int n = c * 16 + ln16;
        short8 bh = *(const short8*)&mh[n][quad * 8];
        short8 bl = *(const short8*)&ml[n][quad * 8];
        acc[c] = MFMA(ah0, bh, acc[c], 0, 0, 0);
        acc[c] = MFMA(ah0, bl, acc[c], 0, 0, 0);
        acc[c] = MFMA(al0, bh, acc[c], 0, 0, 0);
    }
    #pragma unroll
    for (int c = 0; c < 4; c++) {
        const int n = c * 16 + ln16;
        short8 bh = *(const short8*)&mh[n][32 + quad * 8];
        short8 bl = *(const short8*)&ml[n][32 + quad * 8];
        acc[c] = MFMA(ah1, bh, acc[c], 0, 0, 0);
        acc[c] = MFMA(ah1, bl, acc[c], 0, 0, 0);
        acc[c] = MFMA(al1, bh, acc[c], 0, 0, 0);
    }

    #pragma unroll
    for (int c = 0; c < 4; c++) {
        const int n = c * 16 + ln16;
        const int o0 = w * 16 + quad * 4;
        float4 o;
        o.x = acc[c][0] + bvote_s[o0];
        o.y = acc[c][1] + bvote_s[o0 + 1];
        o.z = acc[c][2] + bvote_s[o0 + 2];
        o.w = acc[c][3] + bvote_s[o0 + 3];
        *(float4*)&V[(((size_t)l * K_DIM + k) * nchunk + n0l + n) * O_DIM + o0] = o;
    }
}

// ---------------------------------------------------------------------------
// Kernel C (RESTORED round-3 version — the 54 us C): one block per n, 512 thr
// (8 waves). thread = (k = t>>5, o-pair = t&31); Vr = 32 x float2.
// fa_s/bu_s in LDS; R_s[32][17]; 62-shfl fold E-step; direct a_acc M-step.
// (Round-4's Rfa/RfaBu rework correlated with C 54->83 us and FETCH 66->128MB
// across R4/R6/R7 regardless of B variant and V layout — reverted.)
// ---------------------------------------------------------------------------
__global__ __launch_bounds__(512, 4) void kernelC(
    const float* __restrict__ V, const float* __restrict__ fa_in,
    const float* __restrict__ beta_use, const float* __restrict__ beta_ign,
    const int* __restrict__ iters_p,
    float* __restrict__ out, int nbase, int nchunk)
{
    const int nl   = blockIdx.x;
    const int ng   = nbase + nl;
    const int t    = threadIdx.x;     // 0..511
    const int k    = t >> 5;          // capsule, one per 32-lane half-wave
    const int op   = t & 31;          // o-pair index
    const int o0   = op * 2;
    const int lane = t & 63;
    int iters = iters_p[0];
    if (iters < 0 || iters > 16) iters = 3;

    __shared__ float fa_s[32];
    __shared__ float bu_s[32];
    __shared__ float R_s[32][17];
    __shared__ float sc_s[32][17];

    if (t < 32) {
        fa_s[t] = fa_in[(size_t)t * nchunk + nl];
        bu_s[t] = beta_use[t];
    }
    R_s[t >> 4][t & 15] = 1.f / 16.f;   // 512 threads cover 32x16 exactly
    const float bi_k = beta_ign[k];

    // V[l][k][n][o]: per l, each half-wave reads 32 consecutive float2
    float2 Vr[32];
    #pragma unroll
    for (int l = 0; l < 32; l++)
        Vr[l] = *(const float2*)&V[(((size_t)l * K_DIM + k) * nchunk + nl) * O_DIM + o0];
    __syncthreads();

    float mu0 = 0.f, mu1 = 0.f, var0 = 0.f, var1 = 0.f, a_r = 0.f;

    for (int it = 0; it < iters; it++) {
        if (it > 0) {
            float g0 = 1.f / (2.f * var0 + EPSF);
            float g1 = 1.f / (2.f * var1 + EPSF);
            float lvp = logf(var0 + EPSF) + logf(var1 + EPSF);
            lvp += __shfl_xor(lvp, 1, 64);
            lvp += __shfl_xor(lvp, 2, 64);
            lvp += __shfl_xor(lvp, 4, 64);
            lvp += __shfl_xor(lvp, 8, 64);
            lvp += __shfl_xor(lvp, 16, 64);
            float ls = fminf(a_r, 0.f) - log1pf(expf(-fabsf(a_r)));
            const float cst = ls - 1.f - 1.57079632679f - 0.5f * lvp;

            // ---- fold: 32 per-l partials over 32 lanes, 62 shfls total ----
            const bool s16 = (lane & 16) != 0;
            const bool s8  = (lane & 8)  != 0;
            const bool s4  = (lane & 4)  != 0;
            const bool s2  = (lane & 2)  != 0;
            const bool s1  = (lane & 1)  != 0;
            float w16[16];
            #pragma unroll
            for (int j = 0; j < 16; j++) {
                float d0 = Vr[j].x - mu0,      d1 = Vr[j].y - mu1;
                float a  = d0 * d0 * g0 + d1 * d1 * g1;
                float e0 = Vr[j + 16].x - mu0, e1 = Vr[j + 16].y - mu1;
                float b  = e0 * e0 * g0 + e1 * e1 * g1;
                float ta = a + __shfl_xor(a, 16, 64);
                float tb = b + __shfl_xor(b, 16, 64);
                w16[j] = s16 ? tb : ta;
            }
            float w8[8];
            #pragma unroll
            for (int j = 0; j < 8; j++) {
                float ta = w16[j]     + __shfl_xor(w16[j],     8, 64);
                float tb = w16[j + 8] + __shfl_xor(w16[j + 8], 8, 64);
                w8[j] = s8 ? tb : ta;
            }
            float w4[4];
            #pragma unroll
            for (int j = 0; j < 4; j++) {
                float ta = w8[j]     + __shfl_xor(w8[j],     4, 64);
                float tb = w8[j + 4] + __shfl_xor(w8[j + 4], 4, 64);
                w4[j] = s4 ? tb : ta;
            }
            float w2[2];
            #pragma unroll
            for (int j = 0; j < 2; j++) {
                float ta = w2[0];  // placeholder to keep shape; overwritten below
                (void)ta;
                float taa = w4[j]     + __shfl_xor(w4[j],     2, 64);
                float tbb = w4[j + 2] + __shfl_xor(w4[j + 2], 2, 64);
                w2[j] = s2 ? tbb : taa;
            }
            float ta2 = w2[0] + __shfl_xor(w2[0], 1, 64);
            float tb2 = w2[1] + __shfl_xor(w2[1], 1, 64);
            float w1 = s1 ? tb2 : ta2;
            // lane g (g = lane&31) now holds sum over all o for l = g
            sc_s[lane & 31][k] = cst - w1;
            __syncthreads();

            {   // softmax over k: row l = t>>4, 16 threads per row (one k each)
                const int lr = t >> 4;
                const int kk = t & 15;
                float s0 = sc_s[lr][kk];
                float m = s0;
                m = fmaxf(m, __shfl_xor(m, 1, 64));
                m = fmaxf(m, __shfl_xor(m, 2, 64));
                m = fmaxf(m, __shfl_xor(m, 4, 64));
                m = fmaxf(m, __shfl_xor(m, 8, 64));
                float e = expf(s0 - m);
                float sum = e;
                sum += __shfl_xor(sum, 1, 64);
                sum += __shfl_xor(sum, 2, 64);
                sum += __shfl_xor(sum, 4, 64);
                sum += __shfl_xor(sum, 8, 64);
                R_s[lr][kk] = e / sum;
            }
            __syncthreads();
        }
        float denom = EPSF, a_acc = 0.f;
        float mua0 = 0.f, mua1 = 0.f, v2a0 = 0.f, v2a1 = 0.f;
        #pragma unroll
        for (int l = 0; l < 32; l++) {
            float Du = fa_s[l] * R_s[l][k];
            denom += Du;
            a_acc += bu_s[l] * Du - bi_k * (fa_s[l] - Du);
            float dv0 = Du * Vr[l].x;
            float dv1 = Du * Vr[l].y;
            mua0 += dv0;  v2a0 += dv0 * Vr[l].x;
            mua1 += dv1;  v2a1 += dv1 * Vr[l].y;
        }
        float invd = 1.f / denom;
        mu0 = mua0 * invd;
        mu1 = mua1 * invd;
        var0 = fmaxf(v2a0 * invd - mu0 * mu0, 0.f);
        var1 = fmaxf(v2a1 * invd - mu1 * mu1, 0.f);
        a_r = a_acc;
    }

    if (op == 0) out[(size_t)ng * K_DIM + k] = a_r;
    float2 o2; o2.x = mu0; o2.y = mu1;
    *(float2*)&out[(size_t)N_DIM * K_DIM + ((size_t)ng * K_DIM + k) * O_DIM + o0] = o2;
}

extern "C" void kernel_launch(void* const* d_in, const int* in_sizes, int n_in,
                              void* d_out, int out_size, void* d_ws, size_t ws_size,
                              hipStream_t stream) {
    (void)out_size;
    static const int EXP[11] = {25165824, 32768, 24576, 32, 1572864, 64,
                                2097152, 65536, 32, 16, 1};
    int mapi[11];
    bool used[64] = {false};
    for (int s = 0; s < 11; s++) {
        mapi[s] = (s < n_in) ? s : 0;
        for (int j = 0; j < n_in && j < 64; j++) {
            if (!used[j] && in_sizes[j] == EXP[s]) { mapi[s] = j; used[j] = true; break; }
        }
    }
    const float* x        = (const float*)d_in[mapi[0]];
    const float* mask     = (const float*)d_in[mapi[1]];
    const float* Wscore   = (const float*)d_in[mapi[2]];
    const float* Bscore   = (const float*)d_in[mapi[3]];
    const float* Wcap     = (const float*)d_in[mapi[4]];
    const float* Bcap     = (const float*)d_in[mapi[5]];
    const float* Wvote    = (const float*)d_in[mapi[6]];
    const float* Bvote    = (const float*)d_in[mapi[7]];
    const float* beta_use = (const float*)d_in[mapi[8]];
    const float* beta_ign = (const float*)d_in[mapi[9]];
    const int*   iters    = (const int*)d_in[mapi[10]];
    float* out = (float*)d_out;

    const size_t WCAP = (size_t)L_DIM * I_DIM * D_DIM;         // u16 elems
    const size_t WVOT = (size_t)L_DIM * K_DIM * O_DIM * I_DIM; // u16 elems
    const size_t WBYTES = 2 * WCAP * 2 + 2 * WVOT * 2;

    int C = 64;
    {
        const int cands[5] = {1024, 512, 256, 128, 64};
        for (int i = 0; i < 5; i++) {
            size_t need = WBYTES + (size_t)cands[i] * (128 + 8192 + 131072);
            if (need <= ws_size) { C = cands[i]; break; }
        }
    }

    char* ws = (char*)d_ws;
    u16* WcH = (u16*)ws;
    u16* WcL = (u16*)(ws + WCAP * 2);
    u16* WvH = (u16*)(ws + WCAP * 4);
    u16* WvL = (u16*)(ws + WCAP * 4 + WVOT * 2);
    char* dyn = ws + WBYTES;
    float* fa = (float*)dyn;
    float* mu = (float*)(dyn + (size_t)128 * C);
    float* V  = (float*)(dyn + (size_t)128 * C + (size_t)8192 * C);

    prep_w<<<dim3(28, 32), 256, 0, stream>>>(Wcap, WcH, WcL, Wvote, WvH, WvL);

    for (int nbase = 0; nbase < N_DIM; nbase += C) {
        kernelA<<<dim3(C / 32, 32), 256, 0, stream>>>(
            x, mask, Wscore, Bscore, WcH, WcL, Bcap, mu, fa, nbase, C);
        kernelB<<<dim3(C / 64, 16, 32), 256, 0, stream>>>(
            mu, WvH, WvL, Bvote, V, C);
        kernelC<<<dim3(C), 512, 0, stream>>>(
            V, fa, beta_use, beta_ign, iters, out, nbase, C);
    }
}

// Round 9
// 265.497 us; speedup vs baseline: 1.2585x; 1.0000x over previous
//
#include <hip/hip_runtime.h>
#include <hip/hip_bf16.h>

#define L_DIM 32
#define N_DIM 1024
#define D_DIM 768
#define K_DIM 16
#define I_DIM 64
#define O_DIM 64
#define EPSF 1e-8f
#define PX 72   // padded LDS row (bf16 elems): 144 B

typedef unsigned short u16;
typedef __attribute__((ext_vector_type(8))) short short8;   // 8 bf16 (4 VGPRs)
typedef __attribute__((ext_vector_type(4))) float f32x4;
#define MFMA __builtin_amdgcn_mfma_f32_16x16x32_bf16

__device__ __forceinline__ float bf2f(u16 v) {
    union { unsigned int u; float f; } x; x.u = ((unsigned int)v) << 16; return x.f;
}
__device__ __forceinline__ u16 f2bf(float f) {
    union { float f; unsigned int u; } x; x.f = f;
    unsigned int u = x.u;
    u += 0x7FFFu + ((u >> 16) & 1u);   // RNE
    return (u16)(u >> 16);
}
__device__ __forceinline__ void split2(float v, u16& h, u16& l) {
    u16 hh = f2bf(v);
    h = hh;
    l = f2bf(v - bf2f(hh));
}
// cheap truncation split of float4 -> packed hi uint2 + lo uint2 (exact residual)
__device__ __forceinline__ void store_split4(u16* ph, u16* pl, float4 v) {
    unsigned u0 = __float_as_uint(v.x), u1 = __float_as_uint(v.y);
    unsigned u2 = __float_as_uint(v.z), u3 = __float_as_uint(v.w);
    uint2 H, L;
    H.x = (u0 >> 16) | (u1 & 0xFFFF0000u);
    H.y = (u2 >> 16) | (u3 & 0xFFFF0000u);
    float l0 = v.x - __uint_as_float(u0 & 0xFFFF0000u);
    float l1 = v.y - __uint_as_float(u1 & 0xFFFF0000u);
    float l2 = v.z - __uint_as_float(u2 & 0xFFFF0000u);
    float l3 = v.w - __uint_as_float(u3 & 0xFFFF0000u);
    L.x = (__float_as_uint(l0) >> 16) | (__float_as_uint(l1) & 0xFFFF0000u);
    L.y = (__float_as_uint(l2) >> 16) | (__float_as_uint(l3) & 0xFFFF0000u);
    *(uint2*)ph = H;
    *(uint2*)pl = L;
}

// ---------------------------------------------------------------------------
// Prep (merged): blockIdx.x < 12 -> Wcap [l][d][i] -> [l][i][d] hi/lo
//                blockIdx.x >= 12 -> Wvote [l][k][i][o] -> [l][k][o][i] hi/lo
// grid (28, 32), 256 thr. Branch is block-uniform.
// ---------------------------------------------------------------------------
__global__ __launch_bounds__(256) void prep_w(
    const float* __restrict__ Wc, u16* __restrict__ cH, u16* __restrict__ cL,
    const float* __restrict__ Wv, u16* __restrict__ vH, u16* __restrict__ vL)
{
    const int l = blockIdx.y, t = threadIdx.x;
    __shared__ float tile[64][65];
    if (blockIdx.x < 12) {
        const int d0 = blockIdx.x * 64;
        #pragma unroll
        for (int p = 0; p < 4; p++) {
            int dd = p * 16 + (t >> 4), i4 = (t & 15) * 4;
            float4 v = *(const float4*)&Wc[((size_t)l * D_DIM + d0 + dd) * I_DIM + i4];
            tile[dd][i4] = v.x; tile[dd][i4+1] = v.y; tile[dd][i4+2] = v.z; tile[dd][i4+3] = v.w;
        }
        __syncthreads();
        #pragma unroll
        for (int p = 0; p < 4; p++) {
            int i = p * 16 + (t >> 4), dd0 = (t & 15) * 4;
            u16 h[4], lo[4];
            #pragma unroll
            for (int j = 0; j < 4; j++) split2(tile[dd0 + j][i], h[j], lo[j]);
            size_t base = ((size_t)l * I_DIM + i) * D_DIM + d0 + dd0;
            uint2 ph; ph.x = h[0] | ((unsigned)h[1] << 16); ph.y = h[2] | ((unsigned)h[3] << 16);
            uint2 pl; pl.x = lo[0] | ((unsigned)lo[1] << 16); pl.y = lo[2] | ((unsigned)lo[3] << 16);
            *(uint2*)&cH[base] = ph;
            *(uint2*)&cL[base] = pl;
        }
    } else {
        const int k = blockIdx.x - 12;
        #pragma unroll
        for (int p = 0; p < 4; p++) {
            int i = p * 16 + (t >> 4), o4 = (t & 15) * 4;
            float4 v = *(const float4*)&Wv[(((size_t)l * K_DIM + k) * I_DIM + i) * O_DIM + o4];
            tile[i][o4] = v.x; tile[i][o4+1] = v.y; tile[i][o4+2] = v.z; tile[i][o4+3] = v.w;
        }
        __syncthreads();
        #pragma unroll
        for (int p = 0; p < 4; p++) {
            int o = p * 16 + (t >> 4), i0 = (t & 15) * 4;
            u16 h[4], lo[4];
            #pragma unroll
            for (int j = 0; j < 4; j++) split2(tile[i0 + j][o], h[j], lo[j]);
            size_t base = (((size_t)l * K_DIM + k) * O_DIM + o) * I_DIM + i0;
            uint2 ph; ph.x = h[0] | ((unsigned)h[1] << 16); ph.y = h[2] | ((unsigned)h[3] << 16);
            uint2 pl; pl.x = lo[0] | ((unsigned)lo[1] << 16); pl.y = lo[2] | ((unsigned)lo[3] << 16);
            *(uint2*)&vH[base] = ph;
            *(uint2*)&vL[base] = pl;
        }
    }
}

// ---------------------------------------------------------------------------
// Kernel A (round-1 version — best measured A):
// MFMA, 32-n tile, depth-2 reg pipeline for x AND weights, 1 barrier/chunk,
// XCD-swizzled block mapping.
// ---------------------------------------------------------------------------
#define A_CHUNK(K0, R0, R1, WH0, WL0, WH1, WL1, BUF)                        \
  {                                                                          \
    const float* wp = &wsc_s[(K0) + sd];                                     \
    fa0 += R0.x * wp[0] + R0.y * wp[1] + R0.z * wp[2] + R0.w * wp[3];        \
    fa1 += R1.x * wp[0] + R1.y * wp[1] + R1.z * wp[2] + R1.w * wp[3];        \
    store_split4(&xh[BUF][sg][sd],      &xl[BUF][sg][sd],      R0);          \
    store_split4(&xh[BUF][16 + sg][sd], &xl[BUF][16 + sg][sd], R1);          \
    __syncthreads();                                                         \
    if ((K0) + 128 < D_DIM) {                                                \
      R0 = *(const float4*)&x[xoff0 + (K0) + 128 + sd];                      \
      R1 = *(const float4*)&x[xoff1 + (K0) + 128 + sd];                      \
    }                                                                        \
    {                                                                        \
      short8 bh, bl;                                                         \
      bh = *(const short8*)&xh[BUF][ln16][quad * 8];                         \
      bl = *(const short8*)&xl[BUF][ln16][quad * 8];                         \
      acc0 = MFMA(WH0, bh, acc0, 0, 0, 0);                                   \
      acc0 = MFMA(WH0, bl, acc0, 0, 0, 0);                                   \
      acc0 = MFMA(WL0, bh, acc0, 0, 0, 0);                                   \
      bh = *(const short8*)&xh[BUF][16 + ln16][quad * 8];                    \
      bl = *(const short8*)&xl[BUF][16 + ln16][quad * 8];                    \
      acc1 = MFMA(WH0, bh, acc1, 0, 0, 0);                                   \
      acc1 = MFMA(WH0, bl, acc1, 0, 0, 0);                                   \
      acc1 = MFMA(WL0, bh, acc1, 0, 0, 0);                                   \
      bh = *(const short8*)&xh[BUF][ln16][32 + quad * 8];                    \
      bl = *(const short8*)&xl[BUF][ln16][32 + quad * 8];                    \
      acc0 = MFMA(WH1, bh, acc0, 0, 0, 0);                                   \
      acc0 = MFMA(WH1, bl, acc0, 0, 0, 0);                                   \
      acc0 = MFMA(WL1, bh, acc0, 0, 0, 0);                                   \
      bh = *(const short8*)&xh[BUF][16 + ln16][32 + quad * 8];               \
      bl = *(const short8*)&xl[BUF][16 + ln16][32 + quad * 8];               \
      acc1 = MFMA(WH1, bh, acc1, 0, 0, 0);                                   \
      acc1 = MFMA(WH1, bl, acc1, 0, 0, 0);                                   \
      acc1 = MFMA(WL1, bh, acc1, 0, 0, 0);                                   \
    }                                                                        \
    if ((K0) + 128 < D_DIM) {                                                \
      WH0 = *(const short8*)&WcH[wrow + (K0) + 128];                         \
      WL0 = *(const short8*)&WcL[wrow + (K0) + 128];                         \
      WH1 = *(const short8*)&WcH[wrow + (K0) + 160];                         \
      WL1 = *(const short8*)&WcL[wrow + (K0) + 160];                         \
    }                                                                        \
  }

__global__ __launch_bounds__(256, 4) void kernelA(
    const float* __restrict__ x, const float* __restrict__ mask,
    const float* __restrict__ Wscore, const float* __restrict__ Bscore,
    const u16* __restrict__ WcH, const u16* __restrict__ WcL,
    const float* __restrict__ Bcap,
    float* __restrict__ mu_out, float* __restrict__ fa_out,
    int nbase, int nchunk)
{
    const int bid  = blockIdx.y * gridDim.x + blockIdx.x;
    const int slot = bid >> 3;
    const int l    = (bid & 7) + 8 * (slot & 3);
    const int n0l  = (slot >> 2) * 32;

    const int t    = threadIdx.x;
    const int w    = t >> 6;
    const int lane = t & 63;
    const int quad = lane >> 4;
    const int ln16 = lane & 15;

    __shared__ u16 xh[2][32][PX], xl[2][32][PX];
    __shared__ float wsc_s[D_DIM];
    __shared__ float bcap_s[64];

    for (int i = t; i < D_DIM; i += 256) wsc_s[i] = Wscore[l * D_DIM + i];
    if (t < 64) bcap_s[t] = Bcap[l * I_DIM + t];

    const int sg = t >> 4;          // staging row group 0..15
    const int sd = (t & 15) * 4;    // staging col offset

    const size_t xoff0 = ((size_t)(nbase + n0l + sg) * L_DIM + l) * D_DIM;
    const size_t xoff1 = ((size_t)(nbase + n0l + 16 + sg) * L_DIM + l) * D_DIM;

    float4 r0a = *(const float4*)&x[xoff0 + sd];
    float4 r1a = *(const float4*)&x[xoff1 + sd];
    float4 r0b = *(const float4*)&x[xoff0 + 64 + sd];
    float4 r1b = *(const float4*)&x[xoff1 + 64 + sd];

    const size_t wrow = ((size_t)l * I_DIM + (w * 16 + ln16)) * D_DIM + quad * 8;
    short8 wha0 = *(const short8*)&WcH[wrow];
    short8 wla0 = *(const short8*)&WcL[wrow];
    short8 wha1 = *(const short8*)&WcH[wrow + 32];
    short8 wla1 = *(const short8*)&WcL[wrow + 32];
    short8 whb0 = *(const short8*)&WcH[wrow + 64];
    short8 wlb0 = *(const short8*)&WcL[wrow + 64];
    short8 whb1 = *(const short8*)&WcH[wrow + 96];
    short8 wlb1 = *(const short8*)&WcL[wrow + 96];

    __syncthreads();   // wsc_s / bcap_s ready

    f32x4 acc0 = {0.f, 0.f, 0.f, 0.f};
    f32x4 acc1 = {0.f, 0.f, 0.f, 0.f};
    float fa0 = 0.f, fa1 = 0.f;

    #pragma unroll
    for (int cc = 0; cc < 6; cc++) {
        A_CHUNK(cc * 128,      r0a, r1a, wha0, wla0, wha1, wla1, 0)
        A_CHUNK(cc * 128 + 64, r0b, r1b, whb0, wlb0, whb1, wlb1, 1)
    }

    fa0 += __shfl_xor(fa0, 1, 64); fa1 += __shfl_xor(fa1, 1, 64);
    fa0 += __shfl_xor(fa0, 2, 64); fa1 += __shfl_xor(fa1, 2, 64);
    fa0 += __shfl_xor(fa0, 4, 64); fa1 += __shfl_xor(fa1, 4, 64);
    fa0 += __shfl_xor(fa0, 8, 64); fa1 += __shfl_xor(fa1, 8, 64);
    if ((t & 15) == 0) {
        float bs = Bscore[l];
        {
            float a = fa0 + bs;
            float sig = 1.f / (1.f + expf(-a));
            float m = mask[(size_t)(nbase + n0l + sg) * L_DIM + l];
            fa_out[(size_t)l * nchunk + n0l + sg] = sig * m;
        }
        {
            float a = fa1 + bs;
            float sig = 1.f / (1.f + expf(-a));
            float m = mask[(size_t)(nbase + n0l + 16 + sg) * L_DIM + l];
            fa_out[(size_t)l * nchunk + n0l + 16 + sg] = sig * m;
        }
    }

    #pragma unroll
    for (int c = 0; c < 2; c++) {
        const f32x4 a = (c == 0) ? acc0 : acc1;
        const int n = c * 16 + ln16;
        const int i0 = w * 16 + quad * 4;
        float4 o;
        float* op = (float*)&o;
        #pragma unroll
        for (int r = 0; r < 4; r++) {
            float v = a[r] + bcap_s[i0 + r];
            op[r] = 0.5f * v * (1.f + erff(v * 0.70710678118f));
        }
        *(float4*)&mu_out[((size_t)l * nchunk + n0l + n) * I_DIM + i0] = o;
    }
}

// ---------------------------------------------------------------------------
// Kernel B v6 (REINTRODUCED): V[l][k][n][o] = mu·Wvote + Bvote.
// 4 capsules per block: mu tile staged ONCE, reused for 4 k's (48 MFMAs/block
// vs 12); weight frags for k+1 prefetched into alternate regs during k's
// MFMAs. grid (nchunk/64, 4, 32) = 2048 blocks. XCD-swizzled.
// R7 falsified the "fast B shifts writeback into C" theory (C-R4 stayed at
// 83us with slow B) — B-v6 was never shown to harm a good C. This round
// tests B-v6 + C-R3 for the first time.
// ---------------------------------------------------------------------------
#define B_STEP(KK, AH0, AL0, AH1, AL1, NH0, NL0, NH1, NL1, PRE)              \
  {                                                                          \
    if (PRE) {                                                               \
      const size_t wn = wrow0 + (size_t)((KK) + 1) * (O_DIM * I_DIM);        \
      NH0 = *(const short8*)&WvH[wn];                                        \
      NL0 = *(const short8*)&WvL[wn];                                        \
      NH1 = *(const short8*)&WvH[wn + 32];                                   \
      NL1 = *(const short8*)&WvL[wn + 32];                                   \
    }                                                                        \
    f32x4 acc[4] = {{0.f,0.f,0.f,0.f},{0.f,0.f,0.f,0.f},                     \
                    {0.f,0.f,0.f,0.f},{0.f,0.f,0.f,0.f}};                    \
    _Pragma("unroll")                                                        \
    for (int c = 0; c < 4; c++) {                                            \
        const int n = c * 16 + ln16;                                         \
        short8 bh = *(const short8*)&mh[n][quad * 8];                        \
        short8 bl = *(const short8*)&ml[n][quad * 8];                        \
        acc[c] = MFMA(AH0, bh, acc[c], 0, 0, 0);                             \
        acc[c] = MFMA(AH0, bl, acc[c], 0, 0, 0);                             \
        acc[c] = MFMA(AL0, bh, acc[c], 0, 0, 0);                             \
    }                                                                        \
    _Pragma("unroll")                                                        \
    for (int c = 0; c < 4; c++) {                                            \
        const int n = c * 16 + ln16;                                         \
        short8 bh = *(const short8*)&mh[n][32 + quad * 8];                   \
        short8 bl = *(const short8*)&ml[n][32 + quad * 8];                   \
        acc[c] = MFMA(AH1, bh, acc[c], 0, 0, 0);                             \
        acc[c] = MFMA(AH1, bl, acc[c], 0, 0, 0);                             \
        acc[c] = MFMA(AL1, bh, acc[c], 0, 0, 0);                             \
    }                                                                        \
    _Pragma("unroll")                                                        \
    for (int c = 0; c < 4; c++) {                                            \
        const int n = c * 16 + ln16;                                         \
        const int o0 = w * 16 + quad * 4;                                    \
        float4 o;                                                            \
        o.x = acc[c][0] + bvote_s[KK][o0];                                   \
        o.y = acc[c][1] + bvote_s[KK][o0 + 1];                               \
        o.z = acc[c][2] + bvote_s[KK][o0 + 2];                               \
        o.w = acc[c][3] + bvote_s[KK][o0 + 3];                               \
        *(float4*)&V[(((size_t)l * K_DIM + k0 + (KK)) * nchunk + n0l + n)    \
                     * O_DIM + o0] = o;                                      \
    }                                                                        \
  }

__global__ __launch_bounds__(256) void kernelB(
    const float* __restrict__ mu_in,
    const u16* __restrict__ WvH, const u16* __restrict__ WvL,
    const float* __restrict__ Bvote,
    float* __restrict__ V, int nchunk)
{
    const int bid  = (blockIdx.z * gridDim.y + blockIdx.y) * gridDim.x + blockIdx.x;
    const int slot = bid >> 3;
    const int l    = (bid & 7) + 8 * (slot & 3);
    const int rem  = slot >> 2;
    const int kg   = rem & 3;              // k-group: k0 = kg*4
    const int n0l  = (rem >> 2) * 64;
    const int k0   = kg * 4;

    const int t    = threadIdx.x;
    const int w    = t >> 6;
    const int lane = t & 63;
    const int quad = lane >> 4;
    const int ln16 = lane & 15;

    __shared__ u16 mh[64][PX], ml[64][PX];
    __shared__ float bvote_s[4][64];

    // issue all global loads up front: mu tile, k0 weight frags, 4 biases
    const int srow = t >> 4, scol = (t & 15) * 4;
    float4 m0 = *(const float4*)&mu_in[((size_t)l * nchunk + n0l + srow) * I_DIM + scol];
    float4 m1 = *(const float4*)&mu_in[((size_t)l * nchunk + n0l + 16 + srow) * I_DIM + scol];
    float4 m2 = *(const float4*)&mu_in[((size_t)l * nchunk + n0l + 32 + srow) * I_DIM + scol];
    float4 m3 = *(const float4*)&mu_in[((size_t)l * nchunk + n0l + 48 + srow) * I_DIM + scol];

    const size_t wrow0 = (((size_t)l * K_DIM + k0) * O_DIM + (w * 16 + ln16)) * I_DIM + quad * 8;
    short8 ha0 = *(const short8*)&WvH[wrow0];
    short8 la0 = *(const short8*)&WvL[wrow0];
    short8 ha1 = *(const short8*)&WvH[wrow0 + 32];
    short8 la1 = *(const short8*)&WvL[wrow0 + 32];
    short8 hb0, lb0, hb1, lb1;   // alternate set, filled by prefetch

    bvote_s[t >> 6][t & 63] = Bvote[((size_t)l * K_DIM + k0 + (t >> 6)) * O_DIM + (t & 63)];

    store_split4(&mh[srow][scol],      &ml[srow][scol],      m0);
    store_split4(&mh[16 + srow][scol], &ml[16 + srow][scol], m1);
    store_split4(&mh[32 + srow][scol], &ml[32 + srow][scol], m2);
    store_split4(&mh[48 + srow][scol], &ml[48 + srow][scol], m3);
    __syncthreads();

    B_STEP(0, ha0, la0, ha1, la1, hb0, lb0, hb1, lb1, 1)
    B_STEP(1, hb0, lb0, hb1, lb1, ha0, la0, ha1, la1, 1)
    B_STEP(2, ha0, la0, ha1, la1, hb0, lb0, hb1, lb1, 1)
    B_STEP(3, hb0, lb0, hb1, lb1, ha0, la0, ha1, la1, 0)
}

// ---------------------------------------------------------------------------
// Kernel C (round-3 version, unchanged from R8 — the 54 us C): one block per
// n, 512 thr (8 waves). thread = (k = t>>5, o-pair = t&31); Vr = 32 x float2.
// fa_s/bu_s in LDS; R_s[32][17]; 62-shfl fold E-step; direct a_acc M-step.
// ---------------------------------------------------------------------------
__global__ __launch_bounds__(512, 4) void kernelC(
    const float* __restrict__ V, const float* __restrict__ fa_in,
    const float* __restrict__ beta_use, const float* __restrict__ beta_ign,
    const int* __restrict__ iters_p,
    float* __restrict__ out, int nbase, int nchunk)
{
    const int nl   = blockIdx.x;
    const int ng   = nbase + nl;
    const int t    = threadIdx.x;     // 0..511
    const int k    = t >> 5;          // capsule, one per 32-lane half-wave
    const int op   = t & 31;          // o-pair index
    const int o0   = op * 2;
    const int lane = t & 63;
    int iters = iters_p[0];
    if (iters < 0 || iters > 16) iters = 3;

    __shared__ float fa_s[32];
    __shared__ float bu_s[32];
    __shared__ float R_s[32][17];
    __shared__ float sc_s[32][17];

    if (t < 32) {
        fa_s[t] = fa_in[(size_t)t * nchunk + nl];
        bu_s[t] = beta_use[t];
    }
    R_s[t >> 4][t & 15] = 1.f / 16.f;   // 512 threads cover 32x16 exactly
    const float bi_k = beta_ign[k];

    // V[l][k][n][o]: per l, each half-wave reads 32 consecutive float2
    float2 Vr[32];
    #pragma unroll
    for (int l = 0; l < 32; l++)
        Vr[l] = *(const float2*)&V[(((size_t)l * K_DIM + k) * nchunk + nl) * O_DIM + o0];
    __syncthreads();

    float mu0 = 0.f, mu1 = 0.f, var0 = 0.f, var1 = 0.f, a_r = 0.f;

    for (int it = 0; it < iters; it++) {
        if (it > 0) {
            float g0 = 1.f / (2.f * var0 + EPSF);
            float g1 = 1.f / (2.f * var1 + EPSF);
            float lvp = logf(var0 + EPSF) + logf(var1 + EPSF);
            lvp += __shfl_xor(lvp, 1, 64);
            lvp += __shfl_xor(lvp, 2, 64);
            lvp += __shfl_xor(lvp, 4, 64);
            lvp += __shfl_xor(lvp, 8, 64);
            lvp += __shfl_xor(lvp, 16, 64);
            float ls = fminf(a_r, 0.f) - log1pf(expf(-fabsf(a_r)));
            const float cst = ls - 1.f - 1.57079632679f - 0.5f * lvp;

            // ---- fold: 32 per-l partials over 32 lanes, 62 shfls total ----
            const bool s16 = (lane & 16) != 0;
            const bool s8  = (lane & 8)  != 0;
            const bool s4  = (lane & 4)  != 0;
            const bool s2  = (lane & 2)  != 0;
            const bool s1  = (lane & 1)  != 0;
            float w16[16];
            #pragma unroll
            for (int j = 0; j < 16; j++) {
                float d0 = Vr[j].x - mu0,      d1 = Vr[j].y - mu1;
                float a  = d0 * d0 * g0 + d1 * d1 * g1;
                float e0 = Vr[j + 16].x - mu0, e1 = Vr[j + 16].y - mu1;
                float b  = e0 * e0 * g0 + e1 * e1 * g1;
                float ta = a + __shfl_xor(a, 16, 64);
                float tb = b + __shfl_xor(b, 16, 64);
                w16[j] = s16 ? tb : ta;
            }
            float w8[8];
            #pragma unroll
            for (int j = 0; j < 8; j++) {
                float ta = w16[j]     + __shfl_xor(w16[j],     8, 64);
                float tb = w16[j + 8] + __shfl_xor(w16[j + 8], 8, 64);
                w8[j] = s8 ? tb : ta;
            }
            float w4[4];
            #pragma unroll
            for (int j = 0; j < 4; j++) {
                float ta = w8[j]     + __shfl_xor(w8[j],     4, 64);
                float tb = w8[j + 4] + __shfl_xor(w8[j + 4], 4, 64);
                w4[j] = s4 ? tb : ta;
            }
            float w2[2];
            #pragma unroll
            for (int j = 0; j < 2; j++) {
                float taa = w4[j]     + __shfl_xor(w4[j],     2, 64);
                float tbb = w4[j + 2] + __shfl_xor(w4[j + 2], 2, 64);
                w2[j] = s2 ? tbb : taa;
            }
            float ta2 = w2[0] + __shfl_xor(w2[0], 1, 64);
            float tb2 = w2[1] + __shfl_xor(w2[1], 1, 64);
            float w1 = s1 ? tb2 : ta2;
            // lane g (g = lane&31) now holds sum over all o for l = g
            sc_s[lane & 31][k] = cst - w1;
            __syncthreads();

            {   // softmax over k: row l = t>>4, 16 threads per row (one k each)
                const int lr = t >> 4;
                const int kk = t & 15;
                float s0 = sc_s[lr][kk];
                float m = s0;
                m = fmaxf(m, __shfl_xor(m, 1, 64));
                m = fmaxf(m, __shfl_xor(m, 2, 64));
                m = fmaxf(m, __shfl_xor(m, 4, 64));
                m = fmaxf(m, __shfl_xor(m, 8, 64));
                float e = expf(s0 - m);
                float sum = e;
                sum += __shfl_xor(sum, 1, 64);
                sum += __shfl_xor(sum, 2, 64);
                sum += __shfl_xor(sum, 4, 64);
                sum += __shfl_xor(sum, 8, 64);
                R_s[lr][kk] = e / sum;
            }
            __syncthreads();
        }
        float denom = EPSF, a_acc = 0.f;
        float mua0 = 0.f, mua1 = 0.f, v2a0 = 0.f, v2a1 = 0.f;
        #pragma unroll
        for (int l = 0; l < 32; l++) {
            float Du = fa_s[l] * R_s[l][k];
            denom += Du;
            a_acc += bu_s[l] * Du - bi_k * (fa_s[l] - Du);
            float dv0 = Du * Vr[l].x;
            float dv1 = Du * Vr[l].y;
            mua0 += dv0;  v2a0 += dv0 * Vr[l].x;
            mua1 += dv1;  v2a1 += dv1 * Vr[l].y;
        }
        float invd = 1.f / denom;
        mu0 = mua0 * invd;
        mu1 = mua1 * invd;
        var0 = fmaxf(v2a0 * invd - mu0 * mu0, 0.f);
        var1 = fmaxf(v2a1 * invd - mu1 * mu1, 0.f);
        a_r = a_acc;
    }

    if (op == 0) out[(size_t)ng * K_DIM + k] = a_r;
    float2 o2; o2.x = mu0; o2.y = mu1;
    *(float2*)&out[(size_t)N_DIM * K_DIM + ((size_t)ng * K_DIM + k) * O_DIM + o0] = o2;
}

extern "C" void kernel_launch(void* const* d_in, const int* in_sizes, int n_in,
                              void* d_out, int out_size, void* d_ws, size_t ws_size,
                              hipStream_t stream) {
    (void)out_size;
    static const int EXP[11] = {25165824, 32768, 24576, 32, 1572864, 64,
                                2097152, 65536, 32, 16, 1};
    int mapi[11];
    bool used[64] = {false};
    for (int s = 0; s < 11; s++) {
        mapi[s] = (s < n_in) ? s : 0;
        for (int j = 0; j < n_in && j < 64; j++) {
            if (!used[j] && in_sizes[j] == EXP[s]) { mapi[s] = j; used[j] = true; break; }
        }
    }
    const float* x        = (const float*)d_in[mapi[0]];
    const float* mask     = (const float*)d_in[mapi[1]];
    const float* Wscore   = (const float*)d_in[mapi[2]];
    const float* Bscore   = (const float*)d_in[mapi[3]];
    const float* Wcap     = (const float*)d_in[mapi[4]];
    const float* Bcap     = (const float*)d_in[mapi[5]];
    const float* Wvote    = (const float*)d_in[mapi[6]];
    const float* Bvote    = (const float*)d_in[mapi[7]];
    const float* beta_use = (const float*)d_in[mapi[8]];
    const float* beta_ign = (const float*)d_in[mapi[9]];
    const int*   iters    = (const int*)d_in[mapi[10]];
    float* out = (float*)d_out;

    const size_t WCAP = (size_t)L_DIM * I_DIM * D_DIM;         // u16 elems
    const size_t WVOT = (size_t)L_DIM * K_DIM * O_DIM * I_DIM; // u16 elems
    const size_t WBYTES = 2 * WCAP * 2 + 2 * WVOT * 2;

    int C = 64;
    {
        const int cands[5] = {1024, 512, 256, 128, 64};
        for (int i = 0; i < 5; i++) {
            size_t need = WBYTES + (size_t)cands[i] * (128 + 8192 + 131072);
            if (need <= ws_size) { C = cands[i]; break; }
        }
    }

    char* ws = (char*)d_ws;
    u16* WcH = (u16*)ws;
    u16* WcL = (u16*)(ws + WCAP * 2);
    u16* WvH = (u16*)(ws + WCAP * 4);
    u16* WvL = (u16*)(ws + WCAP * 4 + WVOT * 2);
    char* dyn = ws + WBYTES;
    float* fa = (float*)dyn;
    float* mu = (float*)(dyn + (size_t)128 * C);
    float* V  = (float*)(dyn + (size_t)128 * C + (size_t)8192 * C);

    prep_w<<<dim3(28, 32), 256, 0, stream>>>(Wcap, WcH, WcL, Wvote, WvH, WvL);

    for (int nbase = 0; nbase < N_DIM; nbase += C) {
        kernelA<<<dim3(C / 32, 32), 256, 0, stream>>>(
            x, mask, Wscore, Bscore, WcH, WcL, Bcap, mu, fa, nbase, C);
        kernelB<<<dim3(C / 64, 4, 32), 256, 0, stream>>>(
            mu, WvH, WvL, Bvote, V, C);
        kernelC<<<dim3(C), 512, 0, stream>>>(
            V, fa, beta_use, beta_ign, iters, out, nbase, C);
    }
}